// Round 1
// baseline (386.780 us; speedup 1.0000x reference)
//
#include <hip/hip_runtime.h>
#include <hip/hip_bf16.h>
#include <cstdint>
#include <cstddef>

// Problem constants (B=1 implicit)
static constexpr int kT   = 1024;
static constexpr int kCV  = 8;
static constexpr int kDim = 2048;
static constexpr int kNH  = 32;
static constexpr int kHD  = 64;
static constexpr int kW   = 8;
static constexpr int kK   = 2048;   // inner dim of every GEMM

using bf16_t = __hip_bfloat16;

typedef __attribute__((ext_vector_type(8))) __bf16 bf16x8;
typedef __attribute__((ext_vector_type(4))) float  f32x4;

__device__ __forceinline__ float bf_bits_to_f32(unsigned short u) {
    union { unsigned int i; float f; } c;
    c.i = ((unsigned int)u) << 16;
    return c.f;
}

// ---------------------------------------------------------------------------
// Merged fp32 -> bf16 cast for all 6 inputs in ONE launch.
// ---------------------------------------------------------------------------
struct CastArgs {
    const float* src[6];
    bf16_t*      dst[6];
    int          cum[7];   // cumulative 8-elem chunk counts
};

__global__ void cast_all(CastArgs a, int total_chunks) {
    const int c = blockIdx.x * blockDim.x + threadIdx.x;
    if (c >= total_chunks) return;
    int r = 0;
#pragma unroll
    for (int i = 1; i <= 5; ++i) r += (c >= a.cum[i]) ? 1 : 0;
    const int local = c - a.cum[r];
    const float* s = a.src[r] + (size_t)local * 8;
    bf16_t*      d = a.dst[r] + (size_t)local * 8;
    const float4 lo = *reinterpret_cast<const float4*>(s);
    const float4 hi = *reinterpret_cast<const float4*>(s + 4);
    union { bf16_t h[8]; uint4 u; } o;
    o.h[0] = __float2bfloat16(lo.x); o.h[1] = __float2bfloat16(lo.y);
    o.h[2] = __float2bfloat16(lo.z); o.h[3] = __float2bfloat16(lo.w);
    o.h[4] = __float2bfloat16(hi.x); o.h[5] = __float2bfloat16(hi.y);
    o.h[6] = __float2bfloat16(hi.z); o.h[7] = __float2bfloat16(hi.w);
    *reinterpret_cast<uint4*>(d) = o.u;
}

// ---------------------------------------------------------------------------
// 256x256-tile, BK=64, 8-wave deep-pipelined GEMM body (T3+T4+T5).
//   - double-buffered LDS (128 KiB dynamic), tile t in buf t&1
//   - counted vmcnt(8) at the tile boundary: loads for tile t+2 are issued
//     BEFORE the wait, so only tile t+1's 8 loads are drained (never 0)
//   - lgkmcnt(0) + barrier BEFORE issuing t+2's staging protects buf p from
//     being overwritten while other waves still ds_read tile t from it
//   - same XOR swizzle as the verified 128^2 kernel (keyed on row&7; measured
//     0 bank conflicts), same fragment mapping & C/D layout [m89]
// Per wave: output 128x64 = acc[8][4] f32x4; per K-tile 24 ds_read_b128 +
// 64 MFMA (read:MFMA = 0.375).
// ---------------------------------------------------------------------------
__device__ __forceinline__ void gemm256_body(const bf16_t* __restrict__ A,
                                             const bf16_t* __restrict__ Wt,
                                             bf16_t* __restrict__ C,
                                             int bm, int bn, int ldc,
                                             bf16_t* smem) {
    const int tid  = threadIdx.x;
    const int wave = tid >> 6;
    const int lane = tid & 63;
    const int l16  = lane & 15;
    const int quad = lane >> 4;
    const int wm   = (wave >> 2) * 128;   // 0 or 128
    const int wn   = (wave & 3) * 64;     // 0,64,128,192

    f32x4 acc[8][4];
#pragma unroll
    for (int i = 0; i < 8; ++i)
#pragma unroll
        for (int j = 0; j < 4; ++j) acc[i][j] = (f32x4)0.0f;

    // Staging map: per issue i (0..3), chunk c = i*512 + tid; row = c>>3
    // (= i*64 + (tid>>3)), LDS slot jl = c&7 = tid&7. Global slot
    // jg = jl ^ (row&7); i*64 == 0 (mod 8) so one base pointer suffices.
    const int srow = tid >> 3;                    // 0..63
    const int jg   = (tid & 7) ^ (srow & 7);
    const bf16_t* gA = A  + (size_t)(bm + srow) * kK + jg * 8;
    const bf16_t* gB = Wt + (size_t)(bn + srow) * kK + jg * 8;
    const int ldsw = wave * 512;                  // per-issue wave offset (elems)

    auto stage = [&](int kt, int p) {
        const int k0 = kt * 64;
        bf16_t* As = smem + p * 32768;
        bf16_t* Bs = As + 16384;
#pragma unroll
        for (int i = 0; i < 4; ++i)
            __builtin_amdgcn_global_load_lds(
                (const __attribute__((address_space(1))) void*)(gA + (size_t)i * 64 * kK + k0),
                (__attribute__((address_space(3))) void*)(As + i * 4096 + ldsw),
                16, 0, 0);
#pragma unroll
        for (int i = 0; i < 4; ++i)
            __builtin_amdgcn_global_load_lds(
                (const __attribute__((address_space(1))) void*)(gB + (size_t)i * 64 * kK + k0),
                (__attribute__((address_space(3))) void*)(Bs + i * 4096 + ldsw),
                16, 0, 0);
    };

    bf16x8 af[8], bq[4];
    auto rdfrags = [&](int p, int ph) {
        const bf16_t* As = smem + p * 32768;
        const bf16_t* Bs = As + 16384;
        const int jla = (ph * 4 + quad) ^ (l16 & 7);   // swizzled slot
#pragma unroll
        for (int i = 0; i < 8; ++i)
            af[i] = *reinterpret_cast<const bf16x8*>(
                &As[(wm + i * 16 + l16) * 64 + jla * 8]);
#pragma unroll
        for (int j = 0; j < 4; ++j)
            bq[j] = *reinterpret_cast<const bf16x8*>(
                &Bs[(wn + j * 16 + l16) * 64 + jla * 8]);
    };
    auto domfma = [&]() {
#pragma unroll
        for (int i = 0; i < 8; ++i)
#pragma unroll
            for (int j = 0; j < 4; ++j)
                acc[i][j] = __builtin_amdgcn_mfma_f32_16x16x32_bf16(
                    af[i], bq[j], acc[i][j], 0, 0, 0);
    };

    // Prologue: tiles 0 and 1 in flight; wait only for tile 0 (vmcnt(8)).
    stage(0, 0);
    stage(1, 1);
    asm volatile("s_waitcnt vmcnt(8)" ::: "memory");
    __builtin_amdgcn_s_barrier();

    static_assert(kK / 64 == 32, "NT");
    int p = 0;
    for (int t = 0; t < 30; ++t) {
        rdfrags(p, 0);                 // k-slice 0 of tile t
        domfma();
        rdfrags(p, 1);                 // k-slice 1 (last reads of buf p)
        asm volatile("s_waitcnt lgkmcnt(0)" ::: "memory");   // my reads done
        __builtin_amdgcn_s_barrier();                        // all waves done
        stage(t + 2, p);               // overwrite p (safe now)
        __builtin_amdgcn_s_setprio(1);
        domfma();
        __builtin_amdgcn_s_setprio(0);
        asm volatile("s_waitcnt vmcnt(8)" ::: "memory");     // tile t+1 landed
        __builtin_amdgcn_s_barrier();
        p ^= 1;
    }
    // t = 30: no more staging; drain tile 31's loads at boundary.
    rdfrags(p, 0); domfma();
    rdfrags(p, 1);
    __builtin_amdgcn_s_setprio(1);
    domfma();
    __builtin_amdgcn_s_setprio(0);
    asm volatile("s_waitcnt vmcnt(0)" ::: "memory");
    __builtin_amdgcn_s_barrier();
    p ^= 1;
    // t = 31 (last tile)
    rdfrags(p, 0); domfma();
    rdfrags(p, 1); domfma();

    // Epilogue. C/D layout: col = lane&15, row = quad*4 + reg  [m89]
#pragma unroll
    for (int i = 0; i < 8; ++i) {
#pragma unroll
        for (int rr = 0; rr < 4; ++rr) {
            const int row = bm + wm + i * 16 + quad * 4 + rr;
#pragma unroll
            for (int j = 0; j < 4; ++j) {
                const int col = bn + wn + j * 16 + l16;
                C[(size_t)row * ldc + col] = __float2bfloat16(acc[i][j][rr]);
            }
        }
    }
}

// Fused projections with 256^2 tiles:
// blocks 0..511:  kv = chars @ [wk|wv]^T  (M=8192, N=4096 -> 32x16 tiles)
// blocks 512..543: q = x @ wq^T           (M=1024, N=2048 ->  4x8  tiles)
__global__ __launch_bounds__(512, 2) void proj256_kernel(
    const bf16_t* __restrict__ xb, const bf16_t* __restrict__ cb,
    const bf16_t* __restrict__ wqb, const bf16_t* __restrict__ wkvb,
    bf16_t* __restrict__ qb, bf16_t* __restrict__ kvb) {
    extern __shared__ bf16_t smem[];   // 128 KiB: 2 bufs x (A 32K + B 32K)
    const int bid = blockIdx.x;
    if (bid < 512) {
        const int bm = (bid >> 4) * 256;
        const int bn = (bid & 15) * 256;
        gemm256_body(cb, wkvb, kvb, bm, bn, 4096, smem);
    } else {
        const int t  = bid - 512;
        const int bm = (t >> 3) * 256;
        const int bn = (t & 7) * 256;
        gemm256_body(xb, wqb, qb, bm, bn, 2048, smem);
    }
}

// ---------------------------------------------------------------------------
// 128^2 GEMM body (proven in prior rounds), extended with a K-range so
// out_gemm can split-K. ATOMIC epilogue adds into a zeroed fp32 buffer;
// with exactly 2 commutative adds per element the result is deterministic.
// ---------------------------------------------------------------------------
template <bool ATOMIC>
__device__ __forceinline__ void gemm_body128(const bf16_t* __restrict__ A,
                                             const bf16_t* __restrict__ Wt,
                                             float* __restrict__ C,
                                             int bm, int bn, int ldc,
                                             int kbeg, int kend) {
    __shared__ bf16_t As[128 * 64];   // 16 KB
    __shared__ bf16_t Bs[128 * 64];   // 16 KB

    const int tid  = threadIdx.x;
    const int wave = tid >> 6;
    const int lane = tid & 63;
    const int l16  = lane & 15;
    const int quad = lane >> 4;
    const int wm   = (wave >> 1) * 64;
    const int wn   = (wave & 1) * 64;

    f32x4 acc[4][4];
#pragma unroll
    for (int i = 0; i < 4; ++i)
#pragma unroll
        for (int j = 0; j < 4; ++j) acc[i][j] = (f32x4)0.0f;

    const int srow = tid >> 3;                       // 0..31
    const int jgs  = (tid & 7) ^ (srow & 7);
    const bf16_t* gA = A  + (size_t)(bm + srow) * kK + jgs * 8;
    const bf16_t* gB = Wt + (size_t)(bn + srow) * kK + jgs * 8;

    for (int k0 = kbeg; k0 < kend; k0 += 64) {
#pragma unroll
        for (int i = 0; i < 4; ++i) {
            __builtin_amdgcn_global_load_lds(
                (const __attribute__((address_space(1))) void*)(gA + (size_t)i * 32 * kK + k0),
                (__attribute__((address_space(3))) void*)(As + i * 2048 + wave * 512),
                16, 0, 0);
            __builtin_amdgcn_global_load_lds(
                (const __attribute__((address_space(1))) void*)(gB + (size_t)i * 32 * kK + k0),
                (__attribute__((address_space(3))) void*)(Bs + i * 2048 + wave * 512),
                16, 0, 0);
        }
        __syncthreads();

#pragma unroll
        for (int ph = 0; ph < 2; ++ph) {
            bf16x8 af[4], bfr[4];
#pragma unroll
            for (int i = 0; i < 4; ++i) {
                const int jla = (ph * 4 + quad) ^ (l16 & 7);   // swizzled slot
                af[i]  = *reinterpret_cast<const bf16x8*>(
                    &As[(wm + i * 16 + l16) * 64 + jla * 8]);
                bfr[i] = *reinterpret_cast<const bf16x8*>(
                    &Bs[(wn + i * 16 + l16) * 64 + jla * 8]);
            }
#pragma unroll
            for (int i = 0; i < 4; ++i)
#pragma unroll
                for (int j = 0; j < 4; ++j)
                    acc[i][j] = __builtin_amdgcn_mfma_f32_16x16x32_bf16(
                        af[i], bfr[j], acc[i][j], 0, 0, 0);
        }
        __syncthreads();
    }

#pragma unroll
    for (int i = 0; i < 4; ++i) {
#pragma unroll
        for (int rr = 0; rr < 4; ++rr) {
            const int row = bm + wm + i * 16 + quad * 4 + rr;
#pragma unroll
            for (int j = 0; j < 4; ++j) {
                const int col = bn + wn + j * 16 + l16;
                if constexpr (ATOMIC) {
                    atomicAdd(&C[(size_t)row * ldc + col], acc[i][j][rr]);
                } else {
                    C[(size_t)row * ldc + col] = acc[i][j][rr];
                }
            }
        }
    }
}

// Output projection: out[1024,2048] = attn_out @ wo^T, split-K=2 -> 256 blocks
// (fills the whole GPU instead of 128 CUs). out is memset-zeroed on stream.
__global__ __launch_bounds__(256, 3) void out_gemm(
    const bf16_t* __restrict__ ob, const bf16_t* __restrict__ wob,
    float* __restrict__ out) {
    const int tile = blockIdx.x & 127;
    const int ks   = blockIdx.x >> 7;
    const int bm = (tile >> 4) * 128;
    const int bn = (tile & 15) * 128;
    gemm_body128<true>(ob, wob, out, bm, bn, 2048, ks * 1024, ks * 1024 + 1024);
}

// ---------------------------------------------------------------------------
// Sliding-window attention (unchanged; kvb is interleaved).
// ---------------------------------------------------------------------------
static constexpr int kTT   = 16;
static constexpr int kSRC  = kTT + kW - 1;    // 23 source times
static constexpr int kROWS = kSRC * kCV;      // 184 staged rows
static constexpr int kLDK  = 72;              // padded row stride (bf16)

__global__ __launch_bounds__(1024) void attn_kernel(
    const bf16_t* __restrict__ qb,    // [T, 2048]
    const bf16_t* __restrict__ kvb,   // [T*CV, 4096]: [:,0:2048]=k [:,2048:]=v
    bf16_t* __restrict__ ob) {        // [T, 2048]
    __shared__ unsigned short kl[kROWS * kLDK];   // 25.9 KB
    __shared__ unsigned short vl[kROWS * kLDK];   // 25.9 KB
    __shared__ float ql[kTT * 64];                // 4 KB
    __shared__ float al[kTT * 64];                // 4 KB

    const int t0   = blockIdx.x * kTT;
    const int h    = blockIdx.y;
    const int tid  = threadIdx.x;
    const int wave = tid >> 6;
    const int lane = tid & 63;

    ql[tid] = __bfloat162float(qb[(size_t)(t0 + wave) * kDim + h * kHD + lane]);

    const long long grow0 = (long long)(t0 - (kW - 1)) * kCV;
#pragma unroll
    for (int c = tid; c < kROWS * 8; c += 1024) {
        const int r   = c >> 3;
        const int sub = c & 7;
        const long long grow = grow0 + r;
        uint4 kd = make_uint4(0, 0, 0, 0), vd = make_uint4(0, 0, 0, 0);
        if (grow >= 0) {
            const size_t gb = (size_t)grow * 4096 + h * kHD + sub * 8;
            kd = *reinterpret_cast<const uint4*>(kvb + gb);
            vd = *reinterpret_cast<const uint4*>(kvb + gb + 2048);
        }
        *reinterpret_cast<uint4*>(&kl[r * kLDK + sub * 8]) = kd;
        *reinterpret_cast<uint4*>(&vl[r * kLDK + sub * 8]) = vd;
    }
    __syncthreads();

    // Scores: lane = key kk = w*CV+cv -> staged row wave*8 + kk.
    const int r = wave * kCV + lane;
    float s = 0.0f;
#pragma unroll
    for (int c = 0; c < 8; ++c) {
        union { uint4 u; unsigned short us[8]; } kv;
        kv.u = *reinterpret_cast<const uint4*>(&kl[r * kLDK + c * 8]);
        const float4 qa = *reinterpret_cast<const float4*>(&ql[wave * 64 + c * 8]);
        const float4 qc = *reinterpret_cast<const float4*>(&ql[wave * 64 + c * 8 + 4]);
        s += bf_bits_to_f32(kv.us[0]) * qa.x + bf_bits_to_f32(kv.us[1]) * qa.y +
             bf_bits_to_f32(kv.us[2]) * qa.z + bf_bits_to_f32(kv.us[3]) * qa.w +
             bf_bits_to_f32(kv.us[4]) * qc.x + bf_bits_to_f32(kv.us[5]) * qc.y +
             bf_bits_to_f32(kv.us[6]) * qc.z + bf_bits_to_f32(kv.us[7]) * qc.w;
    }
    s *= 0.125f;

    float m = s;
#pragma unroll
    for (int off = 32; off; off >>= 1) m = fmaxf(m, __shfl_xor(m, off));
    const float e = __expf(s - m);
    float sum = e;
#pragma unroll
    for (int off = 32; off; off >>= 1) sum += __shfl_xor(sum, off);
    al[wave * 64 + lane] = e / sum;   // same-wave producer/consumer

    float o = 0.0f;
#pragma unroll
    for (int k2 = 0; k2 < 64; ++k2)
        o += al[wave * 64 + k2] * bf_bits_to_f32(vl[(wave * kCV + k2) * kLDK + lane]);
    ob[(size_t)(t0 + wave) * kDim + h * kHD + lane] = __float2bfloat16(o);
}

// ---------------------------------------------------------------------------
extern "C" void kernel_launch(void* const* d_in, const int* in_sizes, int n_in,
                              void* d_out, int out_size, void* d_ws,
                              size_t ws_size, hipStream_t stream) {
    const float* x     = (const float*)d_in[0];
    const float* chars = (const float*)d_in[1];
    const float* wq    = (const float*)d_in[2];
    const float* wk    = (const float*)d_in[3];
    const float* wv    = (const float*)d_in[4];
    const float* wo    = (const float*)d_in[5];
    float* out = (float*)d_out;

    // Workspace carve-up (~140 MiB total).
    char* p = (char*)d_ws;
    bf16_t* xb   = (bf16_t*)p; p += (size_t)kT * kDim * 2;            // 4 MB
    bf16_t* cb   = (bf16_t*)p; p += (size_t)kT * kCV * kDim * 2;      // 32 MB
    bf16_t* wqb  = (bf16_t*)p; p += (size_t)kDim * kDim * 2;          // 8 MB
    bf16_t* wkvb = (bf16_t*)p; p += (size_t)2 * kDim * kDim * 2;      // 16 MB
    bf16_t* wob  = (bf16_t*)p; p += (size_t)kDim * kDim * 2;          // 8 MB
    bf16_t* qb   = (bf16_t*)p; p += (size_t)kT * kDim * 2;            // 4 MB
    bf16_t* kvb  = (bf16_t*)p; p += (size_t)kT * kCV * 2 * kDim * 2;  // 64 MB
    bf16_t* ob   = (bf16_t*)p; p += (size_t)kT * kDim * 2;            // 4 MB

    // Opt-in to 128 KiB dynamic LDS for the 256^2 kernel (once).
    static int attr_done = 0;
    if (!attr_done) {
        hipFuncSetAttribute(reinterpret_cast<const void*>(proj256_kernel),
                            hipFuncAttributeMaxDynamicSharedMemorySize, 131072);
        attr_done = 1;
    }

    // Zero the fp32 output for the split-K atomic epilogue.
    hipMemsetAsync(out, 0, (size_t)kT * kDim * sizeof(float), stream);

    // One cast launch for all six tensors.
    CastArgs ca;
    ca.src[0] = x;     ca.dst[0] = xb;
    ca.src[1] = chars; ca.dst[1] = cb;
    ca.src[2] = wq;    ca.dst[2] = wqb;
    ca.src[3] = wk;    ca.dst[3] = wkvb;                  // rows 0..2047
    ca.src[4] = wv;    ca.dst[4] = wkvb + (size_t)kDim * kDim;  // rows 2048..
    ca.src[5] = wo;    ca.dst[5] = wob;
    const int sizes[6] = {kT * kDim, kT * kCV * kDim, kDim * kDim,
                          kDim * kDim, kDim * kDim, kDim * kDim};
    int cum = 0;
    ca.cum[0] = 0;
    for (int i = 0; i < 6; ++i) { cum += sizes[i] / 8; ca.cum[i + 1] = cum; }
    cast_all<<<dim3((cum + 255) / 256), dim3(256), 0, stream>>>(ca, cum);

    // Fused k|v (N=4096) + q projections: 512 + 32 blocks of 512 threads.
    proj256_kernel<<<dim3(544), dim3(512), 131072, stream>>>(
        xb, cb, wqb, wkvb, qb, kvb);

    // Sliding-window attention.
    attn_kernel<<<dim3(kT / kTT, kNH), dim3(1024), 0, stream>>>(qb, kvb, ob);

    // Output projection (fp32 out, split-K=2, atomic accumulate).
    out_gemm<<<dim3(256), dim3(256), 0, stream>>>(ob, wob, out);
}

// Round 2
// 371.551 us; speedup vs baseline: 1.0410x; 1.0410x over previous
//
#include <hip/hip_runtime.h>
#include <hip/hip_bf16.h>
#include <cstdint>
#include <cstddef>

// Problem constants (B=1 implicit)
static constexpr int kT   = 1024;
static constexpr int kCV  = 8;
static constexpr int kDim = 2048;
static constexpr int kNH  = 32;
static constexpr int kHD  = 64;
static constexpr int kW   = 8;
static constexpr int kK   = 2048;   // inner dim of every GEMM

using bf16_t = __hip_bfloat16;

typedef __attribute__((ext_vector_type(8))) __bf16 bf16x8;
typedef __attribute__((ext_vector_type(4))) float  f32x4;

__device__ __forceinline__ float bf_bits_to_f32(unsigned short u) {
    union { unsigned int i; float f; } c;
    c.i = ((unsigned int)u) << 16;
    return c.f;
}

// ---------------------------------------------------------------------------
// Merged fp32 -> bf16 cast for all 6 inputs in ONE launch.
// ---------------------------------------------------------------------------
struct CastArgs {
    const float* src[6];
    bf16_t*      dst[6];
    int          cum[7];   // cumulative 8-elem chunk counts
};

__global__ void cast_all(CastArgs a, int total_chunks) {
    const int c = blockIdx.x * blockDim.x + threadIdx.x;
    if (c >= total_chunks) return;
    int r = 0;
#pragma unroll
    for (int i = 1; i <= 5; ++i) r += (c >= a.cum[i]) ? 1 : 0;
    const int local = c - a.cum[r];
    const float* s = a.src[r] + (size_t)local * 8;
    bf16_t*      d = a.dst[r] + (size_t)local * 8;
    const float4 lo = *reinterpret_cast<const float4*>(s);
    const float4 hi = *reinterpret_cast<const float4*>(s + 4);
    union { bf16_t h[8]; uint4 u; } o;
    o.h[0] = __float2bfloat16(lo.x); o.h[1] = __float2bfloat16(lo.y);
    o.h[2] = __float2bfloat16(lo.z); o.h[3] = __float2bfloat16(lo.w);
    o.h[4] = __float2bfloat16(hi.x); o.h[5] = __float2bfloat16(hi.y);
    o.h[6] = __float2bfloat16(hi.z); o.h[7] = __float2bfloat16(hi.w);
    *reinterpret_cast<uint4*>(d) = o.u;
}

// ---------------------------------------------------------------------------
// 8-phase 256x256 GEMM body (T2+T3+T4+T5 per the m201 template).
// 8 waves (2M x 4N), BK=64, double-buffered 128 KiB LDS.
// Per phase: {ds-read frag subtile, stage ONE half-tile (2x global_load_lds),
//             barrier, lgkmcnt(0), setprio(1), 16 MFMA (one C-quadrant x K=64),
//             setprio(0), [vmcnt(4) at tile boundary], barrier}.
// Staging order per tile: (B-hi, B-lo, A-hi, A-lo), lead = 6 half-tiles.
// Slot-deadline analysis: B slots last-read phase 0, rewritten phases 2/3 of
// the tile 2 earlier (>=2-phase gap); A slots last-read phase 3, rewritten
// phases 0/1 of the NEXT tile (>=1 barrier gap). vmcnt(4) at each boundary
// guarantees the next tile's 4 halves landed (2 halves = 4 loads in flight).
// XOR swizzle (slot = kchunk ^ (row&7)) -> 0 bank conflicts (measured R0).
// ---------------------------------------------------------------------------
__device__ __forceinline__ void gemm256_8ph(const bf16_t* __restrict__ A,
                                            const bf16_t* __restrict__ Wt,
                                            bf16_t* __restrict__ C,
                                            int bm, int bn, int ldc,
                                            bf16_t* smem) {
    const int tid  = threadIdx.x;
    const int wave = tid >> 6;
    const int lane = tid & 63;
    const int l16  = lane & 15;
    const int quad = lane >> 4;
    const int wmi  = wave >> 2;          // 0,1  -> 128-row half of C
    const int wni  = wave & 3;           // 0..3 -> 64-col slice of C

    const int slot0 = quad ^ (l16 & 7);  // swizzled k-chunk, ks=0
    const int slot1 = slot0 ^ 4;         // ks=1

    f32x4 acc[8][4];
#pragma unroll
    for (int i = 0; i < 8; ++i)
#pragma unroll
        for (int j = 0; j < 4; ++j) acc[i][j] = (f32x4)0.0f;

    // Staging map (per half-tile = 128 rows x 64 cols): thread handles chunks
    // c = tid and c = tid+512; row = c>>3, LDS slot jl = c&7, global chunk
    // jg = jl ^ (row&7). row&7 = (tid>>3)&7 for both i -> one base pointer.
    const int srow = tid >> 3;                         // 0..63
    const int jg8  = (((tid & 7) ^ (srow & 7))) * 8;
    const bf16_t* gAlo = A  + (size_t)(bm + srow) * kK + jg8;
    const bf16_t* gAhi = gAlo + (size_t)128 * kK;
    const bf16_t* gBlo = Wt + (size_t)(bn + srow) * kK + jg8;
    const bf16_t* gBhi = gBlo + (size_t)128 * kK;
    const int ldsw = wave * 512;

    // LDS (elems): buf p at p*32768; A tile [0,16384) (lo rows 0..127, hi
    // rows 128..255), B tile [16384,32768) (lo/hi likewise).
    auto stageA = [&](int tau, int hs) {
        bf16_t* dst = smem + (tau & 1) * 32768 + hs * 8192 + ldsw;
        const bf16_t* src = (hs ? gAhi : gAlo) + tau * 64;
        __builtin_amdgcn_global_load_lds(
            (const __attribute__((address_space(1))) void*)src,
            (__attribute__((address_space(3))) void*)dst, 16, 0, 0);
        __builtin_amdgcn_global_load_lds(
            (const __attribute__((address_space(1))) void*)(src + (size_t)64 * kK),
            (__attribute__((address_space(3))) void*)(dst + 4096), 16, 0, 0);
    };
    auto stageB = [&](int tau, int hs) {
        bf16_t* dst = smem + (tau & 1) * 32768 + 16384 + hs * 8192 + ldsw;
        const bf16_t* src = (hs ? gBhi : gBlo) + tau * 64;
        __builtin_amdgcn_global_load_lds(
            (const __attribute__((address_space(1))) void*)src,
            (__attribute__((address_space(3))) void*)dst, 16, 0, 0);
        __builtin_amdgcn_global_load_lds(
            (const __attribute__((address_space(1))) void*)(src + (size_t)64 * kK),
            (__attribute__((address_space(3))) void*)(dst + 4096), 16, 0, 0);
    };

    bf16x8 bq0[4], bq1[4];   // B frags for the current tile (read in phase 0)

#define PH(P, Q, STG, VMW)                                                     \
    {                                                                          \
        const bf16_t* Ab = smem + (P) * 32768;                                 \
        const bf16_t* Bb = Ab + 16384;                                         \
        bf16x8 a0[2], a1[2];                                                   \
        _Pragma("unroll")                                                      \
        for (int ii = 0; ii < 2; ++ii) {                                       \
            const int rb = (wmi * 128 + ((Q) * 2 + ii) * 16 + l16) * 64;       \
            a0[ii] = *reinterpret_cast<const bf16x8*>(&Ab[rb + slot0 * 8]);    \
            a1[ii] = *reinterpret_cast<const bf16x8*>(&Ab[rb + slot1 * 8]);    \
        }                                                                      \
        if ((Q) == 0) {                                                        \
            _Pragma("unroll")                                                  \
            for (int j = 0; j < 4; ++j) {                                      \
                const int rb = (wni * 64 + j * 16 + l16) * 64;                 \
                bq0[j] = *reinterpret_cast<const bf16x8*>(&Bb[rb + slot0 * 8]);\
                bq1[j] = *reinterpret_cast<const bf16x8*>(&Bb[rb + slot1 * 8]);\
            }                                                                  \
        }                                                                      \
        STG;                                                                   \
        __builtin_amdgcn_s_barrier();                                          \
        asm volatile("s_waitcnt lgkmcnt(0)" ::: "memory");                     \
        __builtin_amdgcn_s_setprio(1);                                         \
        _Pragma("unroll")                                                      \
        for (int ii = 0; ii < 2; ++ii)                                         \
            _Pragma("unroll")                                                  \
            for (int j = 0; j < 4; ++j)                                        \
                acc[(Q) * 2 + ii][j] = __builtin_amdgcn_mfma_f32_16x16x32_bf16(\
                    a0[ii], bq0[j], acc[(Q) * 2 + ii][j], 0, 0, 0);            \
        _Pragma("unroll")                                                      \
        for (int ii = 0; ii < 2; ++ii)                                         \
            _Pragma("unroll")                                                  \
            for (int j = 0; j < 4; ++j)                                        \
                acc[(Q) * 2 + ii][j] = __builtin_amdgcn_mfma_f32_16x16x32_bf16(\
                    a1[ii], bq1[j], acc[(Q) * 2 + ii][j], 0, 0, 0);            \
        __builtin_amdgcn_s_setprio(0);                                         \
        VMW;                                                                   \
        __builtin_amdgcn_s_barrier();                                          \
    }

#define VM4 asm volatile("s_waitcnt vmcnt(4)" ::: "memory")
#define VM0 asm volatile("s_waitcnt vmcnt(0)" ::: "memory")

    // Prologue: halves 0..5 = B-hi(0), B-lo(0), A-hi(0), A-lo(0), B-hi(1),
    // B-lo(1); vmcnt(4) -> oldest 8 loads (tile 0) landed.
    stageB(0, 1); stageB(0, 0); stageA(0, 1); stageA(0, 0);
    stageB(1, 1); stageB(1, 0);
    VM4;
    __builtin_amdgcn_s_barrier();

    // Main loop: tiles 0..29 (2 per iteration; buffer parity compile-time).
    for (int tt = 0; tt < 15; ++tt) {
        const int t = tt * 2;
        PH(0, 0, stageA(t + 1, 1), (void)0)
        PH(0, 1, stageA(t + 1, 0), (void)0)
        PH(0, 2, stageB(t + 2, 1), (void)0)
        PH(0, 3, stageB(t + 2, 0), VM4)
        PH(1, 0, stageA(t + 2, 1), (void)0)
        PH(1, 1, stageA(t + 2, 0), (void)0)
        PH(1, 2, stageB(t + 3, 1), (void)0)
        PH(1, 3, stageB(t + 3, 0), VM4)
    }
    // Tile 30 (buf 0): stage only A of tile 31; drain at boundary.
    PH(0, 0, stageA(31, 1), (void)0)
    PH(0, 1, stageA(31, 0), (void)0)
    PH(0, 2, (void)0, (void)0)
    PH(0, 3, (void)0, VM0)
    // Tile 31 (buf 1): pure compute.
    PH(1, 0, (void)0, (void)0)
    PH(1, 1, (void)0, (void)0)
    PH(1, 2, (void)0, (void)0)
    PH(1, 3, (void)0, (void)0)

#undef PH
#undef VM4
#undef VM0

    // Epilogue. C/D layout: col = lane&15, row = quad*4 + reg  [m89]
#pragma unroll
    for (int i = 0; i < 8; ++i) {
#pragma unroll
        for (int rr = 0; rr < 4; ++rr) {
            const int row = bm + wmi * 128 + i * 16 + quad * 4 + rr;
#pragma unroll
            for (int j = 0; j < 4; ++j) {
                const int col = bn + wni * 64 + j * 16 + l16;
                C[(size_t)row * ldc + col] = __float2bfloat16(acc[i][j][rr]);
            }
        }
    }
}

// ---------------------------------------------------------------------------
// 8-wave 128x128 tile, 2-barrier GEMM body (proven structure) for the small
// q projection; runs in the tail of the proj launch (quarter-size blocks).
// ---------------------------------------------------------------------------
__device__ __forceinline__ void gemm128_8w(const bf16_t* __restrict__ A,
                                           const bf16_t* __restrict__ Wt,
                                           bf16_t* __restrict__ C,
                                           int bm, int bn, int ldc,
                                           bf16_t* smem) {
    const int tid  = threadIdx.x;
    const int wave = tid >> 6;
    const int lane = tid & 63;
    const int l16  = lane & 15;
    const int quad = lane >> 4;
    const int wmi  = wave >> 2;    // 0,1  -> 64-row half
    const int wni  = wave & 3;     // 0..3 -> 32-col slice

    bf16_t* As = smem;             // 128x64
    bf16_t* Bs = smem + 8192;      // 128x64

    f32x4 acc[4][2];
#pragma unroll
    for (int i = 0; i < 4; ++i)
#pragma unroll
        for (int j = 0; j < 2; ++j) acc[i][j] = (f32x4)0.0f;

    const int srow = tid >> 3;     // 0..63
    const int jg8  = (((tid & 7) ^ (srow & 7))) * 8;
    const bf16_t* gA = A  + (size_t)(bm + srow) * kK + jg8;
    const bf16_t* gB = Wt + (size_t)(bn + srow) * kK + jg8;
    const int ldsw = wave * 512;

    for (int k0 = 0; k0 < kK; k0 += 64) {
#pragma unroll
        for (int i = 0; i < 2; ++i) {
            __builtin_amdgcn_global_load_lds(
                (const __attribute__((address_space(1))) void*)(gA + (size_t)i * 64 * kK + k0),
                (__attribute__((address_space(3))) void*)(As + i * 4096 + ldsw),
                16, 0, 0);
            __builtin_amdgcn_global_load_lds(
                (const __attribute__((address_space(1))) void*)(gB + (size_t)i * 64 * kK + k0),
                (__attribute__((address_space(3))) void*)(Bs + i * 4096 + ldsw),
                16, 0, 0);
        }
        __syncthreads();

#pragma unroll
        for (int ph = 0; ph < 2; ++ph) {
            const int jla = (ph * 4 + quad) ^ (l16 & 7);
            bf16x8 af[4], bfr[2];
#pragma unroll
            for (int i = 0; i < 4; ++i)
                af[i] = *reinterpret_cast<const bf16x8*>(
                    &As[(wmi * 64 + i * 16 + l16) * 64 + jla * 8]);
#pragma unroll
            for (int j = 0; j < 2; ++j)
                bfr[j] = *reinterpret_cast<const bf16x8*>(
                    &Bs[(wni * 32 + j * 16 + l16) * 64 + jla * 8]);
#pragma unroll
            for (int i = 0; i < 4; ++i)
#pragma unroll
                for (int j = 0; j < 2; ++j)
                    acc[i][j] = __builtin_amdgcn_mfma_f32_16x16x32_bf16(
                        af[i], bfr[j], acc[i][j], 0, 0, 0);
        }
        __syncthreads();
    }

#pragma unroll
    for (int i = 0; i < 4; ++i) {
#pragma unroll
        for (int rr = 0; rr < 4; ++rr) {
            const int row = bm + wmi * 64 + i * 16 + quad * 4 + rr;
#pragma unroll
            for (int j = 0; j < 2; ++j) {
                const int col = bn + wni * 32 + j * 16 + l16;
                C[(size_t)row * ldc + col] = __float2bfloat16(acc[i][j][rr]);
            }
        }
    }
}

// Fused projections:
// blocks 0..511  : kv = chars @ [wk|wv]^T, 256^2 8-phase (exactly 2 rounds)
// blocks 512..639: q  = x @ wq^T, 128^2 quarter-blocks filling the tail
__global__ __launch_bounds__(512, 2) void proj8_kernel(
    const bf16_t* __restrict__ xb, const bf16_t* __restrict__ cb,
    const bf16_t* __restrict__ wqb, const bf16_t* __restrict__ wkvb,
    bf16_t* __restrict__ qb, bf16_t* __restrict__ kvb) {
    extern __shared__ bf16_t smem[];   // 128 KiB
    const int bid = blockIdx.x;
    if (bid < 512) {
        const int bm = (bid >> 4) * 256;   // 32 M-tiles (8192 rows)
        const int bn = (bid & 15) * 256;   // 16 N-tiles (N=4096)
        gemm256_8ph(cb, wkvb, kvb, bm, bn, 4096, smem);
    } else {
        const int t  = bid - 512;
        const int bm = (t >> 4) * 128;     // 8 M-tiles (1024 rows)
        const int bn = (t & 15) * 128;     // 16 N-tiles (N=2048)
        gemm128_8w(xb, wqb, qb, bm, bn, 2048, smem);
    }
}

// ---------------------------------------------------------------------------
// 128^2 / 256-thread GEMM body with K-range for split-K out projection.
// ---------------------------------------------------------------------------
__device__ __forceinline__ void gemm_body128(const bf16_t* __restrict__ A,
                                             const bf16_t* __restrict__ Wt,
                                             float* __restrict__ C,
                                             int bm, int bn, int ldc,
                                             int kbeg, int kend) {
    __shared__ bf16_t As[128 * 64];   // 16 KB
    __shared__ bf16_t Bs[128 * 64];   // 16 KB

    const int tid  = threadIdx.x;
    const int wave = tid >> 6;
    const int lane = tid & 63;
    const int l16  = lane & 15;
    const int quad = lane >> 4;
    const int wm   = (wave >> 1) * 64;
    const int wn   = (wave & 1) * 64;

    f32x4 acc[4][4];
#pragma unroll
    for (int i = 0; i < 4; ++i)
#pragma unroll
        for (int j = 0; j < 4; ++j) acc[i][j] = (f32x4)0.0f;

    const int srow = tid >> 3;                       // 0..31
    const int jgs  = (tid & 7) ^ (srow & 7);
    const bf16_t* gA = A  + (size_t)(bm + srow) * kK + jgs * 8;
    const bf16_t* gB = Wt + (size_t)(bn + srow) * kK + jgs * 8;

    for (int k0 = kbeg; k0 < kend; k0 += 64) {
#pragma unroll
        for (int i = 0; i < 4; ++i) {
            __builtin_amdgcn_global_load_lds(
                (const __attribute__((address_space(1))) void*)(gA + (size_t)i * 32 * kK + k0),
                (__attribute__((address_space(3))) void*)(As + i * 2048 + wave * 512),
                16, 0, 0);
            __builtin_amdgcn_global_load_lds(
                (const __attribute__((address_space(1))) void*)(gB + (size_t)i * 32 * kK + k0),
                (__attribute__((address_space(3))) void*)(Bs + i * 2048 + wave * 512),
                16, 0, 0);
        }
        __syncthreads();

#pragma unroll
        for (int ph = 0; ph < 2; ++ph) {
            bf16x8 af[4], bfr[4];
#pragma unroll
            for (int i = 0; i < 4; ++i) {
                const int jla = (ph * 4 + quad) ^ (l16 & 7);
                af[i]  = *reinterpret_cast<const bf16x8*>(
                    &As[(wm + i * 16 + l16) * 64 + jla * 8]);
                bfr[i] = *reinterpret_cast<const bf16x8*>(
                    &Bs[(wn + i * 16 + l16) * 64 + jla * 8]);
            }
#pragma unroll
            for (int i = 0; i < 4; ++i)
#pragma unroll
                for (int j = 0; j < 4; ++j)
                    acc[i][j] = __builtin_amdgcn_mfma_f32_16x16x32_bf16(
                        af[i], bfr[j], acc[i][j], 0, 0, 0);
        }
        __syncthreads();
    }

#pragma unroll
    for (int i = 0; i < 4; ++i) {
#pragma unroll
        for (int rr = 0; rr < 4; ++rr) {
            const int row = bm + wm + i * 16 + quad * 4 + rr;
#pragma unroll
            for (int j = 0; j < 4; ++j) {
                const int col = bn + wn + j * 16 + l16;
                atomicAdd(&C[(size_t)row * ldc + col], acc[i][j][rr]);
            }
        }
    }
}

// Output projection: out[1024,2048] = attn_out @ wo^T, split-K=2 (256 blocks,
// fills the GPU). Deterministic: exactly 2 commutative fp32 adds per element.
__global__ __launch_bounds__(256, 3) void out_gemm(
    const bf16_t* __restrict__ ob, const bf16_t* __restrict__ wob,
    float* __restrict__ out) {
    const int tile = blockIdx.x & 127;
    const int ks   = blockIdx.x >> 7;
    const int bm = (tile >> 4) * 128;
    const int bn = (tile & 15) * 128;
    gemm_body128(ob, wob, out, bm, bn, 2048, ks * 1024, ks * 1024 + 1024);
}

// ---------------------------------------------------------------------------
// Sliding-window attention (unchanged; kvb is interleaved).
// ---------------------------------------------------------------------------
static constexpr int kTT   = 16;
static constexpr int kSRC  = kTT + kW - 1;    // 23 source times
static constexpr int kROWS = kSRC * kCV;      // 184 staged rows
static constexpr int kLDK  = 72;              // padded row stride (bf16)

__global__ __launch_bounds__(1024) void attn_kernel(
    const bf16_t* __restrict__ qb,    // [T, 2048]
    const bf16_t* __restrict__ kvb,   // [T*CV, 4096]: [:,0:2048]=k [:,2048:]=v
    bf16_t* __restrict__ ob) {        // [T, 2048]
    __shared__ unsigned short kl[kROWS * kLDK];   // 25.9 KB
    __shared__ unsigned short vl[kROWS * kLDK];   // 25.9 KB
    __shared__ float ql[kTT * 64];                // 4 KB
    __shared__ float al[kTT * 64];                // 4 KB

    const int t0   = blockIdx.x * kTT;
    const int h    = blockIdx.y;
    const int tid  = threadIdx.x;
    const int wave = tid >> 6;
    const int lane = tid & 63;

    ql[tid] = __bfloat162float(qb[(size_t)(t0 + wave) * kDim + h * kHD + lane]);

    const long long grow0 = (long long)(t0 - (kW - 1)) * kCV;
#pragma unroll
    for (int c = tid; c < kROWS * 8; c += 1024) {
        const int r   = c >> 3;
        const int sub = c & 7;
        const long long grow = grow0 + r;
        uint4 kd = make_uint4(0, 0, 0, 0), vd = make_uint4(0, 0, 0, 0);
        if (grow >= 0) {
            const size_t gb = (size_t)grow * 4096 + h * kHD + sub * 8;
            kd = *reinterpret_cast<const uint4*>(kvb + gb);
            vd = *reinterpret_cast<const uint4*>(kvb + gb + 2048);
        }
        *reinterpret_cast<uint4*>(&kl[r * kLDK + sub * 8]) = kd;
        *reinterpret_cast<uint4*>(&vl[r * kLDK + sub * 8]) = vd;
    }
    __syncthreads();

    // Scores: lane = key kk = w*CV+cv -> staged row wave*8 + kk.
    const int r = wave * kCV + lane;
    float s = 0.0f;
#pragma unroll
    for (int c = 0; c < 8; ++c) {
        union { uint4 u; unsigned short us[8]; } kv;
        kv.u = *reinterpret_cast<const uint4*>(&kl[r * kLDK + c * 8]);
        const float4 qa = *reinterpret_cast<const float4*>(&ql[wave * 64 + c * 8]);
        const float4 qc = *reinterpret_cast<const float4*>(&ql[wave * 64 + c * 8 + 4]);
        s += bf_bits_to_f32(kv.us[0]) * qa.x + bf_bits_to_f32(kv.us[1]) * qa.y +
             bf_bits_to_f32(kv.us[2]) * qa.z + bf_bits_to_f32(kv.us[3]) * qa.w +
             bf_bits_to_f32(kv.us[4]) * qc.x + bf_bits_to_f32(kv.us[5]) * qc.y +
             bf_bits_to_f32(kv.us[6]) * qc.z + bf_bits_to_f32(kv.us[7]) * qc.w;
    }
    s *= 0.125f;

    float m = s;
#pragma unroll
    for (int off = 32; off; off >>= 1) m = fmaxf(m, __shfl_xor(m, off));
    const float e = __expf(s - m);
    float sum = e;
#pragma unroll
    for (int off = 32; off; off >>= 1) sum += __shfl_xor(sum, off);
    al[wave * 64 + lane] = e / sum;   // same-wave producer/consumer

    float o = 0.0f;
#pragma unroll
    for (int k2 = 0; k2 < 64; ++k2)
        o += al[wave * 64 + k2] * bf_bits_to_f32(vl[(wave * kCV + k2) * kLDK + lane]);
    ob[(size_t)(t0 + wave) * kDim + h * kHD + lane] = __float2bfloat16(o);
}

// ---------------------------------------------------------------------------
extern "C" void kernel_launch(void* const* d_in, const int* in_sizes, int n_in,
                              void* d_out, int out_size, void* d_ws,
                              size_t ws_size, hipStream_t stream) {
    const float* x     = (const float*)d_in[0];
    const float* chars = (const float*)d_in[1];
    const float* wq    = (const float*)d_in[2];
    const float* wk    = (const float*)d_in[3];
    const float* wv    = (const float*)d_in[4];
    const float* wo    = (const float*)d_in[5];
    float* out = (float*)d_out;

    // Workspace carve-up (~140 MiB total).
    char* p = (char*)d_ws;
    bf16_t* xb   = (bf16_t*)p; p += (size_t)kT * kDim * 2;            // 4 MB
    bf16_t* cb   = (bf16_t*)p; p += (size_t)kT * kCV * kDim * 2;      // 32 MB
    bf16_t* wqb  = (bf16_t*)p; p += (size_t)kDim * kDim * 2;          // 8 MB
    bf16_t* wkvb = (bf16_t*)p; p += (size_t)2 * kDim * kDim * 2;      // 16 MB
    bf16_t* wob  = (bf16_t*)p; p += (size_t)kDim * kDim * 2;          // 8 MB
    bf16_t* qb   = (bf16_t*)p; p += (size_t)kT * kDim * 2;            // 4 MB
    bf16_t* kvb  = (bf16_t*)p; p += (size_t)kT * kCV * 2 * kDim * 2;  // 64 MB
    bf16_t* ob   = (bf16_t*)p; p += (size_t)kT * kDim * 2;            // 4 MB

    // Opt-in to 128 KiB dynamic LDS (once).
    static int attr_done = 0;
    if (!attr_done) {
        hipFuncSetAttribute(reinterpret_cast<const void*>(proj8_kernel),
                            hipFuncAttributeMaxDynamicSharedMemorySize, 131072);
        attr_done = 1;
    }

    // Zero the fp32 output for the split-K atomic epilogue.
    hipMemsetAsync(out, 0, (size_t)kT * kDim * sizeof(float), stream);

    // One cast launch for all six tensors.
    CastArgs ca;
    ca.src[0] = x;     ca.dst[0] = xb;
    ca.src[1] = chars; ca.dst[1] = cb;
    ca.src[2] = wq;    ca.dst[2] = wqb;
    ca.src[3] = wk;    ca.dst[3] = wkvb;                  // rows 0..2047
    ca.src[4] = wv;    ca.dst[4] = wkvb + (size_t)kDim * kDim;  // rows 2048..
    ca.src[5] = wo;    ca.dst[5] = wob;
    const int sizes[6] = {kT * kDim, kT * kCV * kDim, kDim * kDim,
                          kDim * kDim, kDim * kDim, kDim * kDim};
    int cum = 0;
    ca.cum[0] = 0;
    for (int i = 0; i < 6; ++i) { cum += sizes[i] / 8; ca.cum[i + 1] = cum; }
    cast_all<<<dim3((cum + 255) / 256), dim3(256), 0, stream>>>(ca, cum);

    // Projections: 512 kv blocks (8-phase 256^2) + 128 q tail blocks (128^2).
    proj8_kernel<<<dim3(640), dim3(512), 131072, stream>>>(
        xb, cb, wqb, wkvb, qb, kvb);

    // Sliding-window attention.
    attn_kernel<<<dim3(kT / kTT, kNH), dim3(1024), 0, stream>>>(qb, kvb, ob);

    // Output projection (fp32 out, split-K=2, atomic accumulate).
    out_gemm<<<dim3(256), dim3(256), 0, stream>>>(ob, wob, out);
}

// Round 3
// 370.335 us; speedup vs baseline: 1.0444x; 1.0033x over previous
//
#include <hip/hip_runtime.h>
#include <hip/hip_bf16.h>
#include <cstdint>
#include <cstddef>

// Problem constants (B=1 implicit)
static constexpr int kT   = 1024;
static constexpr int kCV  = 8;
static constexpr int kDim = 2048;
static constexpr int kNH  = 32;
static constexpr int kHD  = 64;
static constexpr int kW   = 8;
static constexpr int kK   = 2048;   // inner dim of every GEMM

using bf16_t = __hip_bfloat16;

typedef __attribute__((ext_vector_type(8))) __bf16 bf16x8;
typedef __attribute__((ext_vector_type(4))) float  f32x4;

__device__ __forceinline__ float bf_bits_to_f32(unsigned short u) {
    union { unsigned int i; float f; } c;
    c.i = ((unsigned int)u) << 16;
    return c.f;
}

// ---------------------------------------------------------------------------
// Merged fp32 -> bf16 cast for all 6 inputs in ONE launch.
// ---------------------------------------------------------------------------
struct CastArgs {
    const float* src[6];
    bf16_t*      dst[6];
    int          cum[7];   // cumulative 8-elem chunk counts
};

__global__ void cast_all(CastArgs a, int total_chunks) {
    const int c = blockIdx.x * blockDim.x + threadIdx.x;
    if (c >= total_chunks) return;
    int r = 0;
#pragma unroll
    for (int i = 1; i <= 5; ++i) r += (c >= a.cum[i]) ? 1 : 0;
    const int local = c - a.cum[r];
    const float* s = a.src[r] + (size_t)local * 8;
    bf16_t*      d = a.dst[r] + (size_t)local * 8;
    const float4 lo = *reinterpret_cast<const float4*>(s);
    const float4 hi = *reinterpret_cast<const float4*>(s + 4);
    union { bf16_t h[8]; uint4 u; } o;
    o.h[0] = __float2bfloat16(lo.x); o.h[1] = __float2bfloat16(lo.y);
    o.h[2] = __float2bfloat16(lo.z); o.h[3] = __float2bfloat16(lo.w);
    o.h[4] = __float2bfloat16(hi.x); o.h[5] = __float2bfloat16(hi.y);
    o.h[6] = __float2bfloat16(hi.z); o.h[7] = __float2bfloat16(hi.w);
    *reinterpret_cast<uint4*>(d) = o.u;
}

// ---------------------------------------------------------------------------
// PROVEN GEMM body (R0, 144.8 us / 45% MfmaUtil / 0 bank conflicts):
// C[128x128 tile] = A[M,K] * Wt[N,K]^T, bf16 in, K = 2048, BK=64.
// XOR-swizzled LDS: staging loads global chunk j^(row&7) into LDS slot j, so
// fragment ds_read_b128s hit all 32 banks 2-way (free) instead of 8-way.
// global_load_lds stays lane-linear on the LDS side (m104 constraint) and the
// permutation is within one 128B row segment -> coalescing preserved.
// ---------------------------------------------------------------------------
template <bool OUT_BF16, typename CT>
__device__ __forceinline__ void gemm_body(const bf16_t* __restrict__ A,
                                          const bf16_t* __restrict__ Wt,
                                          CT* __restrict__ C,
                                          int bm, int bn, int ldc) {
    __shared__ bf16_t As[128 * 64];   // 16 KB
    __shared__ bf16_t Bs[128 * 64];   // 16 KB

    const int tid  = threadIdx.x;
    const int wave = tid >> 6;
    const int lane = tid & 63;
    const int l16  = lane & 15;
    const int quad = lane >> 4;
    const int wm   = (wave >> 1) * 64;
    const int wn   = (wave & 1) * 64;

    f32x4 acc[4][4];
#pragma unroll
    for (int i = 0; i < 4; ++i)
#pragma unroll
        for (int j = 0; j < 4; ++j) acc[i][j] = (f32x4)0.0f;

    // Staging map: LDS chunk c = i*256 + tid (i = 0..3), row = c>>3 (0..127),
    // LDS slot-in-row jl = c&7. Global chunk j_g = jl ^ (row&7); row&7 is
    // (tid>>3)&7 for every i (i*32 = 0 mod 8), so one base pointer suffices.
    const int srow = tid >> 3;                       // 0..31
    const int jg   = (tid & 7) ^ (srow & 7);
    const bf16_t* gA = A  + (size_t)(bm + srow) * kK + jg * 8;
    const bf16_t* gB = Wt + (size_t)(bn + srow) * kK + jg * 8;

    for (int k0 = 0; k0 < kK; k0 += 64) {
#pragma unroll
        for (int i = 0; i < 4; ++i) {
            __builtin_amdgcn_global_load_lds(
                (const __attribute__((address_space(1))) void*)(gA + (size_t)i * 32 * kK + k0),
                (__attribute__((address_space(3))) void*)(As + i * 2048 + wave * 512),
                16, 0, 0);
            __builtin_amdgcn_global_load_lds(
                (const __attribute__((address_space(1))) void*)(gB + (size_t)i * 32 * kK + k0),
                (__attribute__((address_space(3))) void*)(Bs + i * 2048 + wave * 512),
                16, 0, 0);
        }
        __syncthreads();

#pragma unroll
        for (int ph = 0; ph < 2; ++ph) {
            bf16x8 af[4], bfr[4];
#pragma unroll
            for (int i = 0; i < 4; ++i) {
                const int jla = (ph * 4 + quad) ^ (l16 & 7);   // swizzled slot
                af[i]  = *reinterpret_cast<const bf16x8*>(
                    &As[(wm + i * 16 + l16) * 64 + jla * 8]);
                bfr[i] = *reinterpret_cast<const bf16x8*>(
                    &Bs[(wn + i * 16 + l16) * 64 + jla * 8]);
            }
#pragma unroll
            for (int i = 0; i < 4; ++i)
#pragma unroll
                for (int j = 0; j < 4; ++j)
                    acc[i][j] = __builtin_amdgcn_mfma_f32_16x16x32_bf16(
                        af[i], bfr[j], acc[i][j], 0, 0, 0);
        }
        __syncthreads();
    }

    // Epilogue. C/D layout: col = lane&15, row = quad*4 + reg  [m89]
#pragma unroll
    for (int i = 0; i < 4; ++i) {
#pragma unroll
        for (int rr = 0; rr < 4; ++rr) {
            const int row = bm + wm + i * 16 + quad * 4 + rr;
#pragma unroll
            for (int j = 0; j < 4; ++j) {
                const int col = bn + wn + j * 16 + l16;
                if constexpr (OUT_BF16) {
                    C[(size_t)row * ldc + col] = __float2bfloat16(acc[i][j][rr]);
                } else {
                    C[(size_t)row * ldc + col] = acc[i][j][rr];
                }
            }
        }
    }
}

// ---------------------------------------------------------------------------
// Fused projection kernel: blocks 0..2047 compute kv = chars @ [wk|wv]^T
// (N=4096, interleaved kvb[8192][4096]: cols 0..2047 = k, 2048.. = v);
// blocks 2048..2175 compute q = x @ wq^T. One launch saturates all CUs.
// bounds(256,4): LDS 4x32KB = 128 <= 160 KiB, VGPR 68 -> 4 blocks/CU, which
// improves round quantization (2176/1024 = 2.13 rounds vs 2.83 at 3/CU) and
// cross-block overlap of the barrier drain (m114 mechanism).
// ---------------------------------------------------------------------------
__global__ __launch_bounds__(256, 4) void proj_kernel(
    const bf16_t* __restrict__ xb, const bf16_t* __restrict__ cb,
    const bf16_t* __restrict__ wqb, const bf16_t* __restrict__ wkvb,
    bf16_t* __restrict__ qb, bf16_t* __restrict__ kvb) {
    const int bid = blockIdx.x;
    if (bid < 2048) {
        const int bm = (bid >> 5) * 128;   // 64 M-tiles (8192 rows)
        const int bn = (bid & 31) * 128;   // 32 N-tiles (N = 4096)
        gemm_body<true>(cb, wkvb, kvb, bm, bn, 4096);
    } else {
        const int t  = bid - 2048;
        const int bm = (t >> 4) * 128;     // 8 M-tiles (1024 rows)
        const int bn = (t & 15) * 128;     // 16 N-tiles (N = 2048)
        gemm_body<true>(xb, wqb, qb, bm, bn, 2048);
    }
}

// ---------------------------------------------------------------------------
// Output projection, split-N: out[1024,2048] = attn_out @ wo^T (fp32 out).
// 128x64 tiles -> 8 x 32 = 256 blocks (all CUs busy; R0's 128-block version
// left half the GPU idle; R2's atomic split-K paid memset + 4.2M atomics).
// Plain stores, full K per block -> deterministic, no atomics.
// 4 waves: wave quadrant wm in {0,64}, wn in {0,32}; acc[4][2].
// ---------------------------------------------------------------------------
__global__ __launch_bounds__(256, 2) void out_gemm(
    const bf16_t* __restrict__ ob, const bf16_t* __restrict__ wob,
    float* __restrict__ out) {
    __shared__ bf16_t As[128 * 64];   // 16 KB
    __shared__ bf16_t Bs[64 * 64];    // 8 KB

    const int bm = (blockIdx.x >> 5) * 128;
    const int bn = (blockIdx.x & 31) * 64;

    const int tid  = threadIdx.x;
    const int wave = tid >> 6;
    const int lane = tid & 63;
    const int l16  = lane & 15;
    const int quad = lane >> 4;
    const int wm   = (wave >> 1) * 64;
    const int wn   = (wave & 1) * 32;

    f32x4 acc[4][2];
#pragma unroll
    for (int i = 0; i < 4; ++i)
#pragma unroll
        for (int j = 0; j < 2; ++j) acc[i][j] = (f32x4)0.0f;

    const int srow = tid >> 3;                       // 0..31
    const int jg   = (tid & 7) ^ (srow & 7);
    const bf16_t* gA = ob  + (size_t)(bm + srow) * kK + jg * 8;
    const bf16_t* gB = wob + (size_t)(bn + srow) * kK + jg * 8;

    for (int k0 = 0; k0 < kK; k0 += 64) {
#pragma unroll
        for (int i = 0; i < 4; ++i)
            __builtin_amdgcn_global_load_lds(
                (const __attribute__((address_space(1))) void*)(gA + (size_t)i * 32 * kK + k0),
                (__attribute__((address_space(3))) void*)(As + i * 2048 + wave * 512),
                16, 0, 0);
#pragma unroll
        for (int i = 0; i < 2; ++i)
            __builtin_amdgcn_global_load_lds(
                (const __attribute__((address_space(1))) void*)(gB + (size_t)i * 32 * kK + k0),
                (__attribute__((address_space(3))) void*)(Bs + i * 2048 + wave * 512),
                16, 0, 0);
        __syncthreads();

#pragma unroll
        for (int ph = 0; ph < 2; ++ph) {
            const int jla = (ph * 4 + quad) ^ (l16 & 7);
            bf16x8 af[4], bfr[2];
#pragma unroll
            for (int i = 0; i < 4; ++i)
                af[i] = *reinterpret_cast<const bf16x8*>(
                    &As[(wm + i * 16 + l16) * 64 + jla * 8]);
#pragma unroll
            for (int j = 0; j < 2; ++j)
                bfr[j] = *reinterpret_cast<const bf16x8*>(
                    &Bs[(wn + j * 16 + l16) * 64 + jla * 8]);
#pragma unroll
            for (int i = 0; i < 4; ++i)
#pragma unroll
                for (int j = 0; j < 2; ++j)
                    acc[i][j] = __builtin_amdgcn_mfma_f32_16x16x32_bf16(
                        af[i], bfr[j], acc[i][j], 0, 0, 0);
        }
        __syncthreads();
    }

#pragma unroll
    for (int i = 0; i < 4; ++i) {
#pragma unroll
        for (int rr = 0; rr < 4; ++rr) {
            const int row = bm + wm + i * 16 + quad * 4 + rr;
#pragma unroll
            for (int j = 0; j < 2; ++j) {
                const int col = bn + wn + j * 16 + l16;
                out[(size_t)row * 2048 + col] = acc[i][j][rr];
            }
        }
    }
}

// ---------------------------------------------------------------------------
// Sliding-window attention (kvb is interleaved). PV loop now uses 4
// independent accumulators (breaks the 64-long serial fp32 FMA chain).
// ---------------------------------------------------------------------------
static constexpr int kTT   = 16;
static constexpr int kSRC  = kTT + kW - 1;    // 23 source times
static constexpr int kROWS = kSRC * kCV;      // 184 staged rows
static constexpr int kLDK  = 72;              // padded row stride (bf16)

__global__ __launch_bounds__(1024) void attn_kernel(
    const bf16_t* __restrict__ qb,    // [T, 2048]
    const bf16_t* __restrict__ kvb,   // [T*CV, 4096]: [:,0:2048]=k [:,2048:]=v
    bf16_t* __restrict__ ob) {        // [T, 2048]
    __shared__ unsigned short kl[kROWS * kLDK];   // 25.9 KB
    __shared__ unsigned short vl[kROWS * kLDK];   // 25.9 KB
    __shared__ float ql[kTT * 64];                // 4 KB
    __shared__ float al[kTT * 64];                // 4 KB

    const int t0   = blockIdx.x * kTT;
    const int h    = blockIdx.y;
    const int tid  = threadIdx.x;
    const int wave = tid >> 6;
    const int lane = tid & 63;

    ql[tid] = __bfloat162float(qb[(size_t)(t0 + wave) * kDim + h * kHD + lane]);

    const long long grow0 = (long long)(t0 - (kW - 1)) * kCV;
#pragma unroll
    for (int c = tid; c < kROWS * 8; c += 1024) {
        const int r   = c >> 3;
        const int sub = c & 7;
        const long long grow = grow0 + r;
        uint4 kd = make_uint4(0, 0, 0, 0), vd = make_uint4(0, 0, 0, 0);
        if (grow >= 0) {
            const size_t gb = (size_t)grow * 4096 + h * kHD + sub * 8;
            kd = *reinterpret_cast<const uint4*>(kvb + gb);
            vd = *reinterpret_cast<const uint4*>(kvb + gb + 2048);
        }
        *reinterpret_cast<uint4*>(&kl[r * kLDK + sub * 8]) = kd;
        *reinterpret_cast<uint4*>(&vl[r * kLDK + sub * 8]) = vd;
    }
    __syncthreads();

    // Scores: lane = key kk = w*CV+cv -> staged row wave*8 + kk.
    const int r = wave * kCV + lane;
    float s = 0.0f;
#pragma unroll
    for (int c = 0; c < 8; ++c) {
        union { uint4 u; unsigned short us[8]; } kv;
        kv.u = *reinterpret_cast<const uint4*>(&kl[r * kLDK + c * 8]);
        const float4 qa = *reinterpret_cast<const float4*>(&ql[wave * 64 + c * 8]);
        const float4 qc = *reinterpret_cast<const float4*>(&ql[wave * 64 + c * 8 + 4]);
        s += bf_bits_to_f32(kv.us[0]) * qa.x + bf_bits_to_f32(kv.us[1]) * qa.y +
             bf_bits_to_f32(kv.us[2]) * qa.z + bf_bits_to_f32(kv.us[3]) * qa.w +
             bf_bits_to_f32(kv.us[4]) * qc.x + bf_bits_to_f32(kv.us[5]) * qc.y +
             bf_bits_to_f32(kv.us[6]) * qc.z + bf_bits_to_f32(kv.us[7]) * qc.w;
    }
    s *= 0.125f;

    float m = s;
#pragma unroll
    for (int off = 32; off; off >>= 1) m = fmaxf(m, __shfl_xor(m, off));
    const float e = __expf(s - m);
    float sum = e;
#pragma unroll
    for (int off = 32; off; off >>= 1) sum += __shfl_xor(sum, off);
    al[wave * 64 + lane] = e / sum;   // same-wave producer/consumer

    float o0 = 0.0f, o1 = 0.0f, o2 = 0.0f, o3 = 0.0f;
#pragma unroll
    for (int k2 = 0; k2 < 64; k2 += 4) {
        o0 += al[wave * 64 + k2 + 0] *
              bf_bits_to_f32(vl[(wave * kCV + k2 + 0) * kLDK + lane]);
        o1 += al[wave * 64 + k2 + 1] *
              bf_bits_to_f32(vl[(wave * kCV + k2 + 1) * kLDK + lane]);
        o2 += al[wave * 64 + k2 + 2] *
              bf_bits_to_f32(vl[(wave * kCV + k2 + 2) * kLDK + lane]);
        o3 += al[wave * 64 + k2 + 3] *
              bf_bits_to_f32(vl[(wave * kCV + k2 + 3) * kLDK + lane]);
    }
    const float o = (o0 + o1) + (o2 + o3);
    ob[(size_t)(t0 + wave) * kDim + h * kHD + lane] = __float2bfloat16(o);
}

// ---------------------------------------------------------------------------
extern "C" void kernel_launch(void* const* d_in, const int* in_sizes, int n_in,
                              void* d_out, int out_size, void* d_ws,
                              size_t ws_size, hipStream_t stream) {
    const float* x     = (const float*)d_in[0];
    const float* chars = (const float*)d_in[1];
    const float* wq    = (const float*)d_in[2];
    const float* wk    = (const float*)d_in[3];
    const float* wv    = (const float*)d_in[4];
    const float* wo    = (const float*)d_in[5];
    float* out = (float*)d_out;

    // Workspace carve-up (~140 MiB total).
    char* p = (char*)d_ws;
    bf16_t* xb   = (bf16_t*)p; p += (size_t)kT * kDim * 2;            // 4 MB
    bf16_t* cb   = (bf16_t*)p; p += (size_t)kT * kCV * kDim * 2;      // 32 MB
    bf16_t* wqb  = (bf16_t*)p; p += (size_t)kDim * kDim * 2;          // 8 MB
    bf16_t* wkvb = (bf16_t*)p; p += (size_t)2 * kDim * kDim * 2;      // 16 MB
    bf16_t* wob  = (bf16_t*)p; p += (size_t)kDim * kDim * 2;          // 8 MB
    bf16_t* qb   = (bf16_t*)p; p += (size_t)kT * kDim * 2;            // 4 MB
    bf16_t* kvb  = (bf16_t*)p; p += (size_t)kT * kCV * 2 * kDim * 2;  // 64 MB
    bf16_t* ob   = (bf16_t*)p; p += (size_t)kT * kDim * 2;            // 4 MB

    // One cast launch for all six tensors.
    CastArgs ca;
    ca.src[0] = x;     ca.dst[0] = xb;
    ca.src[1] = chars; ca.dst[1] = cb;
    ca.src[2] = wq;    ca.dst[2] = wqb;
    ca.src[3] = wk;    ca.dst[3] = wkvb;                  // rows 0..2047
    ca.src[4] = wv;    ca.dst[4] = wkvb + (size_t)kDim * kDim;  // rows 2048..
    ca.src[5] = wo;    ca.dst[5] = wob;
    const int sizes[6] = {kT * kDim, kT * kCV * kDim, kDim * kDim,
                          kDim * kDim, kDim * kDim, kDim * kDim};
    int cum = 0;
    ca.cum[0] = 0;
    for (int i = 0; i < 6; ++i) { cum += sizes[i] / 8; ca.cum[i + 1] = cum; }
    cast_all<<<dim3((cum + 255) / 256), dim3(256), 0, stream>>>(ca, cum);

    // Fused k|v (N=4096) + q projections: 2048 + 128 blocks, one launch.
    proj_kernel<<<dim3(2176), dim3(256), 0, stream>>>(xb, cb, wqb, wkvb, qb, kvb);

    // Sliding-window attention.
    attn_kernel<<<dim3(kT / kTT, kNH), dim3(1024), 0, stream>>>(qb, kvb, ob);

    // Output projection (fp32 out, split-N, 256 blocks, no atomics).
    out_gemm<<<dim3(256), dim3(256), 0, stream>>>(ob, wob, out);
}

// Round 4
// 359.237 us; speedup vs baseline: 1.0767x; 1.0309x over previous
//
#include <hip/hip_runtime.h>
#include <hip/hip_bf16.h>
#include <cstdint>
#include <cstddef>

// Problem constants (B=1 implicit)
static constexpr int kT   = 1024;
static constexpr int kCV  = 8;
static constexpr int kDim = 2048;
static constexpr int kNH  = 32;
static constexpr int kHD  = 64;
static constexpr int kW   = 8;
static constexpr int kK   = 2048;   // inner dim of every GEMM

using bf16_t = __hip_bfloat16;

typedef __attribute__((ext_vector_type(8))) __bf16 bf16x8;
typedef __attribute__((ext_vector_type(4))) float  f32x4;

__device__ __forceinline__ float bf_bits_to_f32(unsigned short u) {
    union { unsigned int i; float f; } c;
    c.i = ((unsigned int)u) << 16;
    return c.f;
}

// ---------------------------------------------------------------------------
// Merged fp32 -> bf16 cast for all 6 inputs in ONE launch.
// ---------------------------------------------------------------------------
struct CastArgs {
    const float* src[6];
    bf16_t*      dst[6];
    int          cum[7];   // cumulative 8-elem chunk counts
};

__global__ void cast_all(CastArgs a, int total_chunks) {
    const int c = blockIdx.x * blockDim.x + threadIdx.x;
    if (c >= total_chunks) return;
    int r = 0;
#pragma unroll
    for (int i = 1; i <= 5; ++i) r += (c >= a.cum[i]) ? 1 : 0;
    const int local = c - a.cum[r];
    const float* s = a.src[r] + (size_t)local * 8;
    bf16_t*      d = a.dst[r] + (size_t)local * 8;
    const float4 lo = *reinterpret_cast<const float4*>(s);
    const float4 hi = *reinterpret_cast<const float4*>(s + 4);
    union { bf16_t h[8]; uint4 u; } o;
    o.h[0] = __float2bfloat16(lo.x); o.h[1] = __float2bfloat16(lo.y);
    o.h[2] = __float2bfloat16(lo.z); o.h[3] = __float2bfloat16(lo.w);
    o.h[4] = __float2bfloat16(hi.x); o.h[5] = __float2bfloat16(hi.y);
    o.h[6] = __float2bfloat16(hi.z); o.h[7] = __float2bfloat16(hi.w);
    *reinterpret_cast<uint4*>(d) = o.u;
}

// ---------------------------------------------------------------------------
// PROVEN GEMM body (R0, 144.8 us / 45% MfmaUtil / 0 bank conflicts):
// C[128x128 tile] = A[M,K] * Wt[N,K]^T, bf16 in, K = 2048, BK=64.
// XOR-swizzled LDS: staging loads global chunk j^(row&7) into LDS slot j, so
// fragment ds_read_b128s hit all 32 banks 2-way (free) instead of 8-way.
// global_load_lds stays lane-linear on the LDS side (m104 constraint) and the
// permutation is within one 128B row segment -> coalescing preserved.
// ---------------------------------------------------------------------------
template <bool OUT_BF16, typename CT>
__device__ __forceinline__ void gemm_body(const bf16_t* __restrict__ A,
                                          const bf16_t* __restrict__ Wt,
                                          CT* __restrict__ C,
                                          int bm, int bn, int ldc) {
    __shared__ bf16_t As[128 * 64];   // 16 KB
    __shared__ bf16_t Bs[128 * 64];   // 16 KB

    const int tid  = threadIdx.x;
    const int wave = tid >> 6;
    const int lane = tid & 63;
    const int l16  = lane & 15;
    const int quad = lane >> 4;
    const int wm   = (wave >> 1) * 64;
    const int wn   = (wave & 1) * 64;

    f32x4 acc[4][4];
#pragma unroll
    for (int i = 0; i < 4; ++i)
#pragma unroll
        for (int j = 0; j < 4; ++j) acc[i][j] = (f32x4)0.0f;

    // Staging map: LDS chunk c = i*256 + tid (i = 0..3), row = c>>3 (0..127),
    // LDS slot-in-row jl = c&7. Global chunk j_g = jl ^ (row&7); row&7 is
    // (tid>>3)&7 for every i (i*32 = 0 mod 8), so one base pointer suffices.
    const int srow = tid >> 3;                       // 0..31
    const int jg   = (tid & 7) ^ (srow & 7);
    const bf16_t* gA = A  + (size_t)(bm + srow) * kK + jg * 8;
    const bf16_t* gB = Wt + (size_t)(bn + srow) * kK + jg * 8;

    for (int k0 = 0; k0 < kK; k0 += 64) {
#pragma unroll
        for (int i = 0; i < 4; ++i) {
            __builtin_amdgcn_global_load_lds(
                (const __attribute__((address_space(1))) void*)(gA + (size_t)i * 32 * kK + k0),
                (__attribute__((address_space(3))) void*)(As + i * 2048 + wave * 512),
                16, 0, 0);
            __builtin_amdgcn_global_load_lds(
                (const __attribute__((address_space(1))) void*)(gB + (size_t)i * 32 * kK + k0),
                (__attribute__((address_space(3))) void*)(Bs + i * 2048 + wave * 512),
                16, 0, 0);
        }
        __syncthreads();

#pragma unroll
        for (int ph = 0; ph < 2; ++ph) {
            bf16x8 af[4], bfr[4];
#pragma unroll
            for (int i = 0; i < 4; ++i) {
                const int jla = (ph * 4 + quad) ^ (l16 & 7);   // swizzled slot
                af[i]  = *reinterpret_cast<const bf16x8*>(
                    &As[(wm + i * 16 + l16) * 64 + jla * 8]);
                bfr[i] = *reinterpret_cast<const bf16x8*>(
                    &Bs[(wn + i * 16 + l16) * 64 + jla * 8]);
            }
#pragma unroll
            for (int i = 0; i < 4; ++i)
#pragma unroll
                for (int j = 0; j < 4; ++j)
                    acc[i][j] = __builtin_amdgcn_mfma_f32_16x16x32_bf16(
                        af[i], bfr[j], acc[i][j], 0, 0, 0);
        }
        __syncthreads();
    }

    // Epilogue. C/D layout: col = lane&15, row = quad*4 + reg  [m89]
#pragma unroll
    for (int i = 0; i < 4; ++i) {
#pragma unroll
        for (int rr = 0; rr < 4; ++rr) {
            const int row = bm + wm + i * 16 + quad * 4 + rr;
#pragma unroll
            for (int j = 0; j < 4; ++j) {
                const int col = bn + wn + j * 16 + l16;
                if constexpr (OUT_BF16) {
                    C[(size_t)row * ldc + col] = __float2bfloat16(acc[i][j][rr]);
                } else {
                    C[(size_t)row * ldc + col] = acc[i][j][rr];
                }
            }
        }
    }
}

// ---------------------------------------------------------------------------
// Fused projection kernel: blocks 0..2047 compute kv = chars @ [wk|wv]^T
// (N=4096, interleaved kvb[8192][4096]: cols 0..2047 = k, 2048.. = v);
// blocks 2048..2175 compute q = x @ wq^T. One launch saturates all CUs.
// bounds(256,3) is the measured optimum: R0 = 144.8us / FETCH 184MB; the
// bounds(256,4) experiment (R3) gave 148.5us / FETCH 192MB (worse L2 reuse).
// ---------------------------------------------------------------------------
__global__ __launch_bounds__(256, 3) void proj_kernel(
    const bf16_t* __restrict__ xb, const bf16_t* __restrict__ cb,
    const bf16_t* __restrict__ wqb, const bf16_t* __restrict__ wkvb,
    bf16_t* __restrict__ qb, bf16_t* __restrict__ kvb) {
    const int bid = blockIdx.x;
    if (bid < 2048) {
        const int bm = (bid >> 5) * 128;   // 64 M-tiles (8192 rows)
        const int bn = (bid & 31) * 128;   // 32 N-tiles (N = 4096)
        gemm_body<true>(cb, wkvb, kvb, bm, bn, 4096);
    } else {
        const int t  = bid - 2048;
        const int bm = (t >> 4) * 128;     // 8 M-tiles (1024 rows)
        const int bn = (t & 15) * 128;     // 16 N-tiles (N = 2048)
        gemm_body<true>(xb, wqb, qb, bm, bn, 2048);
    }
}

// ---------------------------------------------------------------------------
// Output projection, split-N: out[1024,2048] = attn_out @ wo^T (fp32 out).
// 128x64 tiles -> 8 x 32 = 256 blocks (all CUs busy). Plain stores, full K
// per block -> deterministic, no atomics, no memset.
// 4 waves: wave quadrant wm in {0,64}, wn in {0,32}; acc[4][2].
// ---------------------------------------------------------------------------
__global__ __launch_bounds__(256, 2) void out_gemm(
    const bf16_t* __restrict__ ob, const bf16_t* __restrict__ wob,
    float* __restrict__ out) {
    __shared__ bf16_t As[128 * 64];   // 16 KB
    __shared__ bf16_t Bs[64 * 64];    // 8 KB

    const int bm = (blockIdx.x >> 5) * 128;
    const int bn = (blockIdx.x & 31) * 64;

    const int tid  = threadIdx.x;
    const int wave = tid >> 6;
    const int lane = tid & 63;
    const int l16  = lane & 15;
    const int quad = lane >> 4;
    const int wm   = (wave >> 1) * 64;
    const int wn   = (wave & 1) * 32;

    f32x4 acc[4][2];
#pragma unroll
    for (int i = 0; i < 4; ++i)
#pragma unroll
        for (int j = 0; j < 2; ++j) acc[i][j] = (f32x4)0.0f;

    const int srow = tid >> 3;                       // 0..31
    const int jg   = (tid & 7) ^ (srow & 7);
    const bf16_t* gA = ob  + (size_t)(bm + srow) * kK + jg * 8;
    const bf16_t* gB = wob + (size_t)(bn + srow) * kK + jg * 8;

    for (int k0 = 0; k0 < kK; k0 += 64) {
#pragma unroll
        for (int i = 0; i < 4; ++i)
            __builtin_amdgcn_global_load_lds(
                (const __attribute__((address_space(1))) void*)(gA + (size_t)i * 32 * kK + k0),
                (__attribute__((address_space(3))) void*)(As + i * 2048 + wave * 512),
                16, 0, 0);
#pragma unroll
        for (int i = 0; i < 2; ++i)
            __builtin_amdgcn_global_load_lds(
                (const __attribute__((address_space(1))) void*)(gB + (size_t)i * 32 * kK + k0),
                (__attribute__((address_space(3))) void*)(Bs + i * 2048 + wave * 512),
                16, 0, 0);
        __syncthreads();

#pragma unroll
        for (int ph = 0; ph < 2; ++ph) {
            const int jla = (ph * 4 + quad) ^ (l16 & 7);
            bf16x8 af[4], bfr[2];
#pragma unroll
            for (int i = 0; i < 4; ++i)
                af[i] = *reinterpret_cast<const bf16x8*>(
                    &As[(wm + i * 16 + l16) * 64 + jla * 8]);
#pragma unroll
            for (int j = 0; j < 2; ++j)
                bfr[j] = *reinterpret_cast<const bf16x8*>(
                    &Bs[(wn + j * 16 + l16) * 64 + jla * 8]);
#pragma unroll
            for (int i = 0; i < 4; ++i)
#pragma unroll
                for (int j = 0; j < 2; ++j)
                    acc[i][j] = __builtin_amdgcn_mfma_f32_16x16x32_bf16(
                        af[i], bfr[j], acc[i][j], 0, 0, 0);
        }
        __syncthreads();
    }

#pragma unroll
    for (int i = 0; i < 4; ++i) {
#pragma unroll
        for (int rr = 0; rr < 4; ++rr) {
            const int row = bm + wm + i * 16 + quad * 4 + rr;
#pragma unroll
            for (int j = 0; j < 2; ++j) {
                const int col = bn + wn + j * 16 + l16;
                out[(size_t)row * 2048 + col] = acc[i][j][rr];
            }
        }
    }
}

// ---------------------------------------------------------------------------
// Sliding-window attention (kvb is interleaved). PV loop uses 4 independent
// accumulators (breaks the 64-long serial fp32 FMA chain).
// ---------------------------------------------------------------------------
static constexpr int kTT   = 16;
static constexpr int kSRC  = kTT + kW - 1;    // 23 source times
static constexpr int kROWS = kSRC * kCV;      // 184 staged rows
static constexpr int kLDK  = 72;              // padded row stride (bf16)

__global__ __launch_bounds__(1024) void attn_kernel(
    const bf16_t* __restrict__ qb,    // [T, 2048]
    const bf16_t* __restrict__ kvb,   // [T*CV, 4096]: [:,0:2048]=k [:,2048:]=v
    bf16_t* __restrict__ ob) {        // [T, 2048]
    __shared__ unsigned short kl[kROWS * kLDK];   // 25.9 KB
    __shared__ unsigned short vl[kROWS * kLDK];   // 25.9 KB
    __shared__ float ql[kTT * 64];                // 4 KB
    __shared__ float al[kTT * 64];                // 4 KB

    const int t0   = blockIdx.x * kTT;
    const int h    = blockIdx.y;
    const int tid  = threadIdx.x;
    const int wave = tid >> 6;
    const int lane = tid & 63;

    ql[tid] = __bfloat162float(qb[(size_t)(t0 + wave) * kDim + h * kHD + lane]);

    const long long grow0 = (long long)(t0 - (kW - 1)) * kCV;
#pragma unroll
    for (int c = tid; c < kROWS * 8; c += 1024) {
        const int r   = c >> 3;
        const int sub = c & 7;
        const long long grow = grow0 + r;
        uint4 kd = make_uint4(0, 0, 0, 0), vd = make_uint4(0, 0, 0, 0);
        if (grow >= 0) {
            const size_t gb = (size_t)grow * 4096 + h * kHD + sub * 8;
            kd = *reinterpret_cast<const uint4*>(kvb + gb);
            vd = *reinterpret_cast<const uint4*>(kvb + gb + 2048);
        }
        *reinterpret_cast<uint4*>(&kl[r * kLDK + sub * 8]) = kd;
        *reinterpret_cast<uint4*>(&vl[r * kLDK + sub * 8]) = vd;
    }
    __syncthreads();

    // Scores: lane = key kk = w*CV+cv -> staged row wave*8 + kk.
    const int r = wave * kCV + lane;
    float s = 0.0f;
#pragma unroll
    for (int c = 0; c < 8; ++c) {
        union { uint4 u; unsigned short us[8]; } kv;
        kv.u = *reinterpret_cast<const uint4*>(&kl[r * kLDK + c * 8]);
        const float4 qa = *reinterpret_cast<const float4*>(&ql[wave * 64 + c * 8]);
        const float4 qc = *reinterpret_cast<const float4*>(&ql[wave * 64 + c * 8 + 4]);
        s += bf_bits_to_f32(kv.us[0]) * qa.x + bf_bits_to_f32(kv.us[1]) * qa.y +
             bf_bits_to_f32(kv.us[2]) * qa.z + bf_bits_to_f32(kv.us[3]) * qa.w +
             bf_bits_to_f32(kv.us[4]) * qc.x + bf_bits_to_f32(kv.us[5]) * qc.y +
             bf_bits_to_f32(kv.us[6]) * qc.z + bf_bits_to_f32(kv.us[7]) * qc.w;
    }
    s *= 0.125f;

    float m = s;
#pragma unroll
    for (int off = 32; off; off >>= 1) m = fmaxf(m, __shfl_xor(m, off));
    const float e = __expf(s - m);
    float sum = e;
#pragma unroll
    for (int off = 32; off; off >>= 1) sum += __shfl_xor(sum, off);
    al[wave * 64 + lane] = e / sum;   // same-wave producer/consumer

    float o0 = 0.0f, o1 = 0.0f, o2 = 0.0f, o3 = 0.0f;
#pragma unroll
    for (int k2 = 0; k2 < 64; k2 += 4) {
        o0 += al[wave * 64 + k2 + 0] *
              bf_bits_to_f32(vl[(wave * kCV + k2 + 0) * kLDK + lane]);
        o1 += al[wave * 64 + k2 + 1] *
              bf_bits_to_f32(vl[(wave * kCV + k2 + 1) * kLDK + lane]);
        o2 += al[wave * 64 + k2 + 2] *
              bf_bits_to_f32(vl[(wave * kCV + k2 + 2) * kLDK + lane]);
        o3 += al[wave * 64 + k2 + 3] *
              bf_bits_to_f32(vl[(wave * kCV + k2 + 3) * kLDK + lane]);
    }
    const float o = (o0 + o1) + (o2 + o3);
    ob[(size_t)(t0 + wave) * kDim + h * kHD + lane] = __float2bfloat16(o);
}

// ---------------------------------------------------------------------------
extern "C" void kernel_launch(void* const* d_in, const int* in_sizes, int n_in,
                              void* d_out, int out_size, void* d_ws,
                              size_t ws_size, hipStream_t stream) {
    const float* x     = (const float*)d_in[0];
    const float* chars = (const float*)d_in[1];
    const float* wq    = (const float*)d_in[2];
    const float* wk    = (const float*)d_in[3];
    const float* wv    = (const float*)d_in[4];
    const float* wo    = (const float*)d_in[5];
    float* out = (float*)d_out;

    // Workspace carve-up (~140 MiB total).
    char* p = (char*)d_ws;
    bf16_t* xb   = (bf16_t*)p; p += (size_t)kT * kDim * 2;            // 4 MB
    bf16_t* cb   = (bf16_t*)p; p += (size_t)kT * kCV * kDim * 2;      // 32 MB
    bf16_t* wqb  = (bf16_t*)p; p += (size_t)kDim * kDim * 2;          // 8 MB
    bf16_t* wkvb = (bf16_t*)p; p += (size_t)2 * kDim * kDim * 2;      // 16 MB
    bf16_t* wob  = (bf16_t*)p; p += (size_t)kDim * kDim * 2;          // 8 MB
    bf16_t* qb   = (bf16_t*)p; p += (size_t)kT * kDim * 2;            // 4 MB
    bf16_t* kvb  = (bf16_t*)p; p += (size_t)kT * kCV * 2 * kDim * 2;  // 64 MB
    bf16_t* ob   = (bf16_t*)p; p += (size_t)kT * kDim * 2;            // 4 MB

    // One cast launch for all six tensors.
    CastArgs ca;
    ca.src[0] = x;     ca.dst[0] = xb;
    ca.src[1] = chars; ca.dst[1] = cb;
    ca.src[2] = wq;    ca.dst[2] = wqb;
    ca.src[3] = wk;    ca.dst[3] = wkvb;                  // rows 0..2047
    ca.src[4] = wv;    ca.dst[4] = wkvb + (size_t)kDim * kDim;  // rows 2048..
    ca.src[5] = wo;    ca.dst[5] = wob;
    const int sizes[6] = {kT * kDim, kT * kCV * kDim, kDim * kDim,
                          kDim * kDim, kDim * kDim, kDim * kDim};
    int cum = 0;
    ca.cum[0] = 0;
    for (int i = 0; i < 6; ++i) { cum += sizes[i] / 8; ca.cum[i + 1] = cum; }
    cast_all<<<dim3((cum + 255) / 256), dim3(256), 0, stream>>>(ca, cum);

    // Fused k|v (N=4096) + q projections: 2048 + 128 blocks, one launch.
    proj_kernel<<<dim3(2176), dim3(256), 0, stream>>>(xb, cb, wqb, wkvb, qb, kvb);

    // Sliding-window attention.
    attn_kernel<<<dim3(kT / kTT, kNH), dim3(1024), 0, stream>>>(qb, kvb, ob);

    // Output projection (fp32 out, split-N, 256 blocks, no atomics).
    out_gemm<<<dim3(256), dim3(256), 0, stream>>>(ob, wob, out);
}